// Round 3
// baseline (988.247 us; speedup 1.0000x reference)
//
#include <hip/hip_runtime.h>
#include <math.h>

// ---------------------------------------------------------------------------
// SNN forward: psp (K=100 alpha FIR) -> conv/pool/fc -> spike (refractory scan)
// All arithmetic mirrors the JAX reference's f32 association order.
// Round 13: dense FIR restored (round-10 math, bit-exact); structure split:
//   scan_kernel  — 1 thread/series refractory scan, 5-deep rolling global
//                  prefetch, writes spikes bit-packed 4-per-dword (1B each).
//   fir_kernel   — byte spike tile in LDS (13.6 KB, conflict-free 53-word
//                  stride), dense FIR via v_cvt_f32_ubyte ({0,1} exact).
//   poolfir_kernel — same + in-order quad shuffle pool (*11).
// This removes the in-block scan serialization (was: wave0 scans 7200cyc
// while 7 waves idle) and lifts occupancy 3->4 blocks/CU (52KB->13.6KB LDS).
// ---------------------------------------------------------------------------

#define THETA 10.0f

// HQ[i] = h[i-15] for 15<=i<=114 (h[k] = (k/10)*exp(1-k/10)), else 0. 144 entries.
// rk[i] = REF_KERNEL[i+1] = (-40*(i+1))*exp(1-(i+1)),  i=0..14
// wtN = transposed weights: wt[(ci*K*K + tap)*Co + co] = W[co][ci][tap]
__global__ void prep_kernel(const float* __restrict__ W1, const float* __restrict__ W2,
                            const float* __restrict__ W3, const float* __restrict__ W4,
                            float* HQ, float* rk,
                            float* wt1, float* wt2, float* wt3, float* wt4) {
    int i = blockIdx.x * 256 + threadIdx.x;
    if (i < 144) {
        int k = i - 15;
        float val = 0.0f;
        if (k >= 0 && k <= 99) {
            float tf = (float)k;
            float x = tf / 10.0f;
            val = x * (float)exp((double)(1.0f - x));   // same expr as prior rounds
        }
        HQ[i] = val;
    } else if (i < 160) {
        int j = i - 144;
        if (j < 15) {
            float t = (float)(j + 1);
            rk[j] = (-40.0f * t) * (float)exp((double)(1.0f - t));
        }
    } else if (i < 960) {            // W1: 16 x 50
        int j = i - 160, co = j / 50, tp = j % 50;
        wt1[tp * 16 + co] = W1[j];
    } else if (i < 5568) {           // W2: 32 x 144
        int j = i - 960, co = j / 144, tp = j % 144;
        wt2[tp * 32 + co] = W2[j];
    } else if (i < 24000) {          // W3: 64 x 288
        int j = i - 5568, co = j / 288, tp = j % 288;
        wt3[tp * 64 + co] = W3[j];
    } else if (i < 60864) {          // W4: 64 x 576
        int j = i - 24000, co = j / 576, tp = j % 576;
        wt4[tp * 64 + co] = W4[j];
    }
}

// One scan step; spike bit ORed into W.  Math identical to prior rounds:
// u = x + p[0]; s = (u>=theta); p[i] = fmaf(s, rk[i], p[i+1]); p[14]=s*rk[14].
#define SCANB(XC, BIT, W, p, rk)                                              \
    {                                                                         \
        const float u_ = (XC) + p[0];                                         \
        const bool sp_ = (u_ >= THETA);                                       \
        const float sv_ = sp_ ? 1.0f : 0.0f;                                  \
        W |= sp_ ? (BIT) : 0u;                                                \
        _Pragma("unroll")                                                     \
        for (int i_ = 0; i_ < 14; ++i_) p[i_] = fmaf(sv_, rk[i_], p[i_ + 1]); \
        p[14] = sv_ * rk[14];                                                 \
    }

// Process one float4 quad -> one packed spike dword (bytes = t0..t0+3).
#define QPROC(BV, QI)                                                         \
    {                                                                         \
        unsigned int w_ = 0u;                                                 \
        SCANB(BV.x, 1u, w_, p, rk)                                            \
        SCANB(BV.y, 0x100u, w_, p, rk)                                        \
        SCANB(BV.z, 0x10000u, w_, p, rk)                                      \
        SCANB(BV.w, 0x1000000u, w_, p, rk)                                    \
        sp[QI] = w_;                                                          \
    }

// ---------------------------------------------------------------------------
// Refractory scan, 1 thread = 1 series.  Reads 200 f32 potentials from
// global via a 5-quad rolling register prefetch (loads are state-independent
// so they issue ~640 VALU-cycles ahead of use); writes 50 packed dwords.
// ---------------------------------------------------------------------------
__global__ __launch_bounds__(256) void scan_kernel(const float* __restrict__ v,
                                                   unsigned int* __restrict__ s,
                                                   const float* __restrict__ rkt,
                                                   int n) {
    const int nid = blockIdx.x * 256 + threadIdx.x;
    if (nid >= n) return;
    float rk[15];
    #pragma unroll
    for (int i = 0; i < 15; ++i) rk[i] = rkt[i];
    float p[15];
    #pragma unroll
    for (int i = 0; i < 15; ++i) p[i] = 0.0f;
    const float4* vp4 = reinterpret_cast<const float4*>(v + (long)nid * 200);
    unsigned int* sp = s + (long)nid * 50;
    float4 b0 = vp4[0], b1 = vp4[1], b2 = vp4[2], b3 = vp4[3], b4 = vp4[4];
    #pragma unroll 1
    for (int g = 0; g < 10; ++g) {
        const int q0 = 5 * g;
        QPROC(b0, q0)
        if (g < 9) b0 = vp4[q0 + 5];
        QPROC(b1, q0 + 1)
        if (g < 9) b1 = vp4[q0 + 6];
        QPROC(b2, q0 + 2)
        if (g < 9) b2 = vp4[q0 + 7];
        QPROC(b3, q0 + 3)
        if (g < 9) b3 = vp4[q0 + 8];
        QPROC(b4, q0 + 4)
        if (g < 9) b4 = vp4[q0 + 9];
    }
}

// 16-FMA inner step, order identical to prior rounds (qw,qz,qy,qx; k
// ascending per accumulator).  hA = coeff base vector, hB = next vector.
#define FIR_STEP(A0, A1, A2, A3, qx, qy, qz, qw, hA, hB)  \
    A0 = fmaf(hA.x, qw, A0);                              \
    A1 = fmaf(hA.y, qw, A1);                              \
    A2 = fmaf(hA.z, qw, A2);                              \
    A3 = fmaf(hA.w, qw, A3);                              \
    A0 = fmaf(hA.y, qz, A0);                              \
    A1 = fmaf(hA.z, qz, A1);                              \
    A2 = fmaf(hA.w, qz, A2);                              \
    A3 = fmaf(hB.x, qz, A3);                              \
    A0 = fmaf(hA.z, qy, A0);                              \
    A1 = fmaf(hA.w, qy, A1);                              \
    A2 = fmaf(hB.x, qy, A2);                              \
    A3 = fmaf(hB.y, qy, A3);                              \
    A0 = fmaf(hA.w, qx, A0);                              \
    A1 = fmaf(hB.x, qx, A1);                              \
    A2 = fmaf(hB.y, qx, A2);                              \
    A3 = fmaf(hB.z, qx, A3);

// ---------------------------------------------------------------------------
// Dense FIR item (8 outputs at t0=8*id), byte-spike input.  Per j: one
// ds_read_b32 (4 spike bytes) + 4 v_cvt_f32_ubyte + 32 FMA.  {0,1} values
// are exact through cvt -> identical math to the f32-tile version.
// Row = 53 dwords (odd stride -> lanes hit all 32 banks, 2/bank = free).
// ---------------------------------------------------------------------------
__device__ __forceinline__ void fir_run2b(const unsigned int* __restrict__ rowB,
                                          const float4* __restrict__ HQ4,
                                          int t0, int jend, float4 (&acc)[2]) {
    float4 A = HQ4[2], B = HQ4[3], C = HQ4[4];
    int wi = (t0 >> 2) + 1;
    for (int j = 0; j <= jend; ++j) {
        const unsigned int w = rowB[wi - j];
        const float4 N = HQ4[j + 5];
        const float qx = (float)(w & 0xFFu);
        const float qy = (float)((w >> 8) & 0xFFu);
        const float qz = (float)((w >> 16) & 0xFFu);
        const float qw = (float)((w >> 24) & 0xFFu);
        FIR_STEP(acc[0].x, acc[0].y, acc[0].z, acc[0].w, qx, qy, qz, qw, A, B)
        FIR_STEP(acc[1].x, acc[1].y, acc[1].z, acc[1].w, qx, qy, qz, qw, B, C)
        A = B; B = C; C = N;
    }
}

// Balanced wave->item table (item id i has min(2i,25)+2 j-iters; wave sums
// 60..71 vs avg 63.3).  -1 = no item.
__device__ static const signed char FIR_ITEMS[8][4] = {
    {24, 12, 8, -1}, {22, 21, 4, -1}, {20, 19, 3, -1}, {18, 17, 2, -1},
    {16, 15, 1, 0},  {13, 11, 5, -1}, {14, 10, 6, -1}, {23, 9, 7, -1}};

// ---------------------------------------------------------------------------
// FIR kernel.  Block = 64 series x 8 waves; LDS = byte spike tile only
// (64 x 53 dwords = 13.6 KB -> 4 blocks/CU, wave-limited).
// MODE 0: input = packed spike dwords.  MODE 1: input = f32 {0,1} spikes
// (network input); staged with a != 0 pack, tail-guarded by n.
// ---------------------------------------------------------------------------
template <int MODE>
__global__ __launch_bounds__(512) void fir_kernel(const void* __restrict__ in,
                                                  float* __restrict__ out,
                                                  const float* __restrict__ HQ,
                                                  int n) {
    __shared__ unsigned int tileB[64 * 53];
    const int l = threadIdx.x & 63;
    const int w = threadIdx.x >> 6;
    const int s0 = blockIdx.x * 64;
    if (MODE == 0) {
        const unsigned int* ip = (const unsigned int*)in;
        for (int i = threadIdx.x; i < 3200; i += 512) {
            const int slot = i / 50, q = i - slot * 50;
            tileB[53 * slot + q] = ip[(long)(s0 + slot) * 50 + q];
        }
    } else {
        const float* ip = (const float*)in;
        for (int i = threadIdx.x; i < 3200; i += 512) {
            const int slot = i / 50, q = i - slot * 50;
            const int ser = s0 + slot;
            unsigned int wv = 0u;
            if (ser < n) {
                const float4 v = *reinterpret_cast<const float4*>(ip + (long)ser * 200 + 4 * q);
                wv = (v.x != 0.0f ? 1u : 0u) | (v.y != 0.0f ? 0x100u : 0u) |
                     (v.z != 0.0f ? 0x10000u : 0u) | (v.w != 0.0f ? 0x1000000u : 0u);
            }
            tileB[53 * slot + q] = wv;
        }
    }
    __syncthreads();
    const bool valid = (s0 + l) < n;
    const unsigned int* rowB = tileB + 53 * l;
    const float4* HQ4 = reinterpret_cast<const float4*>(HQ);
    float* op = out + (long)(s0 + l) * 200;
    #pragma unroll
    for (int k = 0; k < 4; ++k) {
        const int id = FIR_ITEMS[w][k];
        if (id < 0) break;
        const int t0 = 8 * id;
        const int jend = ((2 * id < 25) ? 2 * id : 25) + 1;
        float4 acc[2];
        acc[0] = make_float4(0.f, 0.f, 0.f, 0.f);
        acc[1] = make_float4(0.f, 0.f, 0.f, 0.f);
        fir_run2b(rowB, HQ4, t0, jend, acc);
        if (valid) {
            *reinterpret_cast<float4*>(op + t0) = acc[0];
            *reinterpret_cast<float4*>(op + t0 + 4) = acc[1];
        }
    }
}

// ---------------------------------------------------------------------------
// FIR + 2x2 sum-pool (*11).  Block = 16 outputs = 64 input series
// (slot = 4*oi + pixel); input = packed spike dwords (gathered per pixel).
// Pool combine = in-order quad shuffle sum ((p0+p1)+p2)+p3 then *11 —
// bit-identical to unfused.
// ---------------------------------------------------------------------------
__global__ __launch_bounds__(512) void poolfir_kernel(const unsigned int* __restrict__ in,
                                                      float* __restrict__ out,
                                                      const float* __restrict__ HQ,
                                                      int C, int HO, int WO) {
    __shared__ unsigned int tileB[64 * 53];
    const int l = threadIdx.x & 63;
    const int w = threadIdx.x >> 6;
    const int o0 = blockIdx.x * 16;
    const int H = 2 * HO, W = 2 * WO;
    for (int i = threadIdx.x; i < 3200; i += 512) {
        const int slot = i / 50, q = i - slot * 50;
        const int oi = slot >> 2, pq = slot & 3;
        const int o = o0 + oi;
        const int wo = o % WO; int tmp = o / WO;
        const int ho = tmp % HO; tmp /= HO;
        const int c = tmp % C; const int b = tmp / C;
        const long sb = ((long)((b * C + c) * H + 2 * ho + (pq >> 1))) * W + 2 * wo + (pq & 1);
        tileB[53 * slot + q] = in[sb * 50 + q];
    }
    __syncthreads();
    const int qb = l & ~3;
    const unsigned int* rowB = tileB + 53 * l;
    const float4* HQ4 = reinterpret_cast<const float4*>(HQ);
    float* op = out + (long)(o0 + (l >> 2)) * 200;
    auto qsum = [&](float v) -> float {
        const float v0 = __shfl(v, qb + 0);
        const float v1 = __shfl(v, qb + 1);
        const float v2 = __shfl(v, qb + 2);
        const float v3 = __shfl(v, qb + 3);
        return (((v0 + v1) + v2) + v3) * 11.0f;
    };
    #pragma unroll
    for (int k = 0; k < 4; ++k) {
        const int id = FIR_ITEMS[w][k];
        if (id < 0) break;
        const int t0 = 8 * id;
        const int jend = ((2 * id < 25) ? 2 * id : 25) + 1;
        float4 acc[2];
        acc[0] = make_float4(0.f, 0.f, 0.f, 0.f);
        acc[1] = make_float4(0.f, 0.f, 0.f, 0.f);
        fir_run2b(rowB, HQ4, t0, jend, acc);
        #pragma unroll
        for (int d = 0; d < 2; ++d) {
            float4 r;
            r.x = qsum(acc[d].x); r.y = qsum(acc[d].y);
            r.z = qsum(acc[d].z); r.w = qsum(acc[d].w);
            if ((l & 3) == 0)
                *reinterpret_cast<float4*>(op + t0 + 4 * d) = r;
        }
    }
}

// ---------------------------------------------------------------------------
// conv1 (K=5): float4-of-t, transposed weights, 16 co accumulators.
// ---------------------------------------------------------------------------
template <int K, int PAD, int CI, int COG>
__global__ __launch_bounds__(256) void conv_kernel(const float* __restrict__ x,
                                                   const float* __restrict__ wt,
                                                   float* __restrict__ out,
                                                   int Co, int H, int W,
                                                   int HO, int WO) {
    const int l = threadIdx.x & 63;
    const int wv = threadIdx.x >> 6;
    if (l >= 50) return;
    const int p = blockIdx.x * 4 + wv;
    const int wo = p % WO, ho = p / WO;
    const int co0 = blockIdx.y * COG;
    const int b = blockIdx.z;
    const int t0 = l * 4;
    float4 acc[COG];
    #pragma unroll
    for (int c = 0; c < COG; ++c) acc[c] = make_float4(0.f, 0.f, 0.f, 0.f);
    const float* xb = x + ((long)b * CI * H * W) * 200 + t0;
    for (int ci = 0; ci < CI; ++ci) {
        #pragma unroll
        for (int kh = 0; kh < K; ++kh) {
            const int hi = ho + kh - PAD;
            if (hi < 0 || hi >= H) continue;
            #pragma unroll
            for (int kw = 0; kw < K; ++kw) {
                const int wi = wo + kw - PAD;
                if (wi < 0 || wi >= W) continue;
                const float4 v = *reinterpret_cast<const float4*>(
                    xb + ((long)(ci * H + hi) * W + wi) * 200);
                const float* wp = wt + ((ci * K + kh) * K + kw) * Co + co0;
                #pragma unroll
                for (int c = 0; c < COG; ++c) {
                    const float wv_ = wp[c];
                    acc[c].x = fmaf(wv_, v.x, acc[c].x);
                    acc[c].y = fmaf(wv_, v.y, acc[c].y);
                    acc[c].z = fmaf(wv_, v.z, acc[c].z);
                    acc[c].w = fmaf(wv_, v.w, acc[c].w);
                }
            }
        }
    }
    const long hwN = (long)HO * WO;
    const long ob = ((long)(b * Co + co0) * HO + ho) * WO + wo;
    #pragma unroll
    for (int c = 0; c < COG; ++c)
        *reinterpret_cast<float4*>(out + (ob + c * hwN) * 200 + t0) = acc[c];
}

// ---------------------------------------------------------------------------
// K=3 convs: ci-software-pipelined, zero-filled OOB taps (bit-exact).
// ---------------------------------------------------------------------------
template <int CI, int COG>
__global__ __launch_bounds__(256) void conv3_kernel(const float* __restrict__ x,
                                                    const float* __restrict__ wt,
                                                    float* __restrict__ out,
                                                    int Co, int H, int W) {
    const int l = threadIdx.x & 63;
    const int wv = threadIdx.x >> 6;
    if (l >= 50) return;
    const int p = blockIdx.x * 4 + wv;
    const int wo = p % W, ho = p / W;
    const int co0 = blockIdx.y * COG;
    const int b = blockIdx.z;
    const int t0 = l * 4;
    float4 acc[COG];
    #pragma unroll
    for (int c = 0; c < COG; ++c) acc[c] = make_float4(0.f, 0.f, 0.f, 0.f);

    bool vm[9];
    #pragma unroll
    for (int i = 0; i < 9; ++i) {
        const int hi = ho + i / 3 - 1, wi = wo + i % 3 - 1;
        vm[i] = (hi >= 0) && (hi < H) && (wi >= 0) && (wi < W);
    }
    const long cis = (long)H * W * 200;
    const float* pb = x + (long)b * CI * cis + ((long)(ho - 1) * W + (wo - 1)) * 200 + t0;

    float4 bufA[9], bufB[9];
    auto ld = [&](int ci, float4 (&B)[9]) {
        const float* pc = pb + ci * cis;
        #pragma unroll
        for (int i = 0; i < 9; ++i) {
            B[i] = vm[i] ? *reinterpret_cast<const float4*>(pc + ((i / 3) * W + (i % 3)) * 200)
                         : make_float4(0.f, 0.f, 0.f, 0.f);
        }
    };
    auto fm = [&](const float4 (&B)[9], int ci) {
        #pragma unroll
        for (int i = 0; i < 9; ++i) {
            const float* wp = wt + (ci * 9 + i) * Co + co0;
            #pragma unroll
            for (int c = 0; c < COG; ++c) {
                const float wv_ = wp[c];
                acc[c].x = fmaf(wv_, B[i].x, acc[c].x);
                acc[c].y = fmaf(wv_, B[i].y, acc[c].y);
                acc[c].z = fmaf(wv_, B[i].z, acc[c].z);
                acc[c].w = fmaf(wv_, B[i].w, acc[c].w);
            }
        }
    };

    ld(0, bufA);
    #pragma unroll 1
    for (int ci = 0; ci < CI; ci += 2) {
        ld(ci + 1, bufB);
        fm(bufA, ci);
        if (ci + 2 < CI) ld(ci + 2, bufA);
        fm(bufB, ci + 1);
    }

    const long hwN = (long)H * W;
    const long ob = ((long)(b * Co + co0) * H + ho) * W + wo;
    #pragma unroll
    for (int c = 0; c < COG; ++c)
        *reinterpret_cast<float4*>(out + (ob + c * hwN) * 200 + t0) = acc[c];
}

// ---------------------------------------------------------------------------
// Standalone spike scan producing f32 spikes (final fc->spike only).
// ---------------------------------------------------------------------------
__global__ __launch_bounds__(256) void spike_kernel(const float* __restrict__ v,
                                                    float* __restrict__ s,
                                                    const float* __restrict__ rkt,
                                                    int n) {
    const int nid = blockIdx.x * 256 + threadIdx.x;
    if (nid >= n) return;
    float rk[15];
    #pragma unroll
    for (int i = 0; i < 15; ++i) rk[i] = rkt[i];
    float p[15];
    #pragma unroll
    for (int i = 0; i < 15; ++i) p[i] = 0.0f;
    const float* vp = v + (long)nid * 200;
    float* sp = s + (long)nid * 200;
    for (int t = 0; t < 200; ++t) {
        const float u = vp[t] + p[0];
        const float sv = (u >= THETA) ? 1.0f : 0.0f;
        sp[t] = sv;
        #pragma unroll
        for (int i = 0; i < 14; ++i) p[i] = fmaf(sv, rk[i], p[i + 1]);
        p[14] = sv * rk[14];
    }
}

// ---------------------------------------------------------------------------
// FC: out[b,k,t] = sum_m x[b,m,t] * Wfc[k,m], m ascending (2304) — chain
// order unchanged (bit-exact).  LDS t-major xs[q][2308]: lane (k,q) reads
// 4 m's per ds_read_b128 (576 LDS issues vs 2304).  80 active lanes/block.
// ---------------------------------------------------------------------------
__global__ __launch_bounds__(128) void fc_kernel(const float* __restrict__ x,
                                                 const float* __restrict__ wf,
                                                 float* __restrict__ out) {
    __shared__ __align__(16) float xs[8 * 2308];
    const int b = blockIdx.x;          // 4
    const int t0 = blockIdx.y * 8;     // 25 chunks
    const int tid = threadIdx.x;
    const float* xb = x + (long)b * 2304 * 200 + t0;
    for (int i = tid; i < 4608; i += 128) {
        const int m = i >> 1, qh = (i & 1) * 4;
        const float4 v = *reinterpret_cast<const float4*>(xb + (long)m * 200 + qh);
        xs[(qh + 0) * 2308 + m] = v.x;
        xs[(qh + 1) * 2308 + m] = v.y;
        xs[(qh + 2) * 2308 + m] = v.z;
        xs[(qh + 3) * 2308 + m] = v.w;
    }
    __syncthreads();
    if (tid < 80) {
        const int k = tid >> 3, q = tid & 7;
        float a = 0.0f;
        const float* wp = wf + k * 2304;
        const float* xp = xs + q * 2308;
        for (int m4 = 0; m4 < 2304; m4 += 4) {
            const float4 xv = *reinterpret_cast<const float4*>(xp + m4);
            const float4 wv = *reinterpret_cast<const float4*>(wp + m4);
            a = fmaf(wv.x, xv.x, a);
            a = fmaf(wv.y, xv.y, a);
            a = fmaf(wv.z, xv.z, a);
            a = fmaf(wv.w, xv.w, a);
        }
        out[((long)b * 10 + k) * 200 + t0 + q] = a;
    }
}

extern "C" void kernel_launch(void* const* d_in, const int* in_sizes, int n_in,
                              void* d_out, int out_size, void* d_ws, size_t ws_size,
                              hipStream_t stream) {
    const float* x_in = (const float*)d_in[0];  // (4,2,50,50,200)
    const float* W1 = (const float*)d_in[1];    // (16,2,5,5)
    const float* W2 = (const float*)d_in[2];    // (32,16,3,3)
    const float* W3 = (const float*)d_in[3];    // (64,32,3,3)
    const float* W4 = (const float*)d_in[4];    // (64,64,3,3)
    const float* Wfc = (const float*)d_in[5];   // (10,64,6,6)
    float* outp = (float*)d_out;                // (4,10,200)

    float* ws = (float*)d_ws;
    float* HQ  = ws;                  // 144 (16B aligned)
    float* rk  = ws + 144;            // 15 (+1 pad)
    float* wt1 = ws + 160;            // 800
    float* wt2 = wt1 + 800;           // 4608
    float* wt3 = wt2 + 4608;          // 18432
    float* wt4 = wt3 + 18432;         // 36864
    float* A   = wt4 + 36864;         // 7,372,800 floats (spike bytes live here too)
    float* B   = A + 7372800;         // 29,491,200
    float* C   = B + 29491200;        // 14,745,600
    unsigned int* Au = (unsigned int*)A;   // packed spikes: series*50 dwords

    hipLaunchKernelGGL(prep_kernel, dim3(238), dim3(256), 0, stream,
                       W1, W2, W3, W4, HQ, rk, wt1, wt2, wt3, wt4);

    // p0 = psp(input): 20000 series (input is exact {0,1} f32)
    hipLaunchKernelGGL((fir_kernel<1>), dim3(313), dim3(512), 0, stream,
                       x_in, A, HQ, 20000);
    // c1 = conv1(p0): (4,16,48,48,200) -> B
    hipLaunchKernelGGL((conv_kernel<5, 1, 2, 16>), dim3(2304 / 4, 1, 4), dim3(256), 0, stream,
                       A, wt1, B, 16, 50, 50, 48, 48);
    // s1 = spike(c1): 147456 series -> packed bytes in A (exactly 29,491,200 B)
    hipLaunchKernelGGL(scan_kernel, dim3(576), dim3(256), 0, stream, B, Au, rk, 147456);
    // o1 = pool(psp(s1)): 36864 outputs -> C
    hipLaunchKernelGGL(poolfir_kernel, dim3(36864 / 16), dim3(512), 0, stream,
                       Au, C, HQ, 16, 24, 24);
    // s2 = spike(o1): 36864 series -> A
    hipLaunchKernelGGL(scan_kernel, dim3(144), dim3(256), 0, stream, C, Au, rk, 36864);
    // p2 = psp(s2): -> B
    hipLaunchKernelGGL((fir_kernel<0>), dim3(576), dim3(512), 0, stream,
                       Au, B, HQ, 36864);
    // c2 = conv2(p2): (4,32,24,24,200) -> C
    hipLaunchKernelGGL((conv3_kernel<16, 8>), dim3(576 / 4, 4, 4), dim3(256), 0, stream,
                       B, wt2, C, 32, 24, 24);
    // s3 = spike(c2): 73728 series -> A
    hipLaunchKernelGGL(scan_kernel, dim3(288), dim3(256), 0, stream, C, Au, rk, 73728);
    // o2 = pool(psp(s3)): 18432 outputs -> B
    hipLaunchKernelGGL(poolfir_kernel, dim3(18432 / 16), dim3(512), 0, stream,
                       Au, B, HQ, 32, 12, 12);
    // s4 = spike(o2): 18432 series -> A
    hipLaunchKernelGGL(scan_kernel, dim3(72), dim3(256), 0, stream, B, Au, rk, 18432);
    // p4 = psp(s4): -> C
    hipLaunchKernelGGL((fir_kernel<0>), dim3(288), dim3(512), 0, stream,
                       Au, C, HQ, 18432);
    // c3 = conv3(p4): (4,64,12,12,200) -> B
    hipLaunchKernelGGL((conv3_kernel<32, 8>), dim3(144 / 4, 8, 4), dim3(256), 0, stream,
                       C, wt3, B, 64, 12, 12);
    // s5 = spike(c3): 36864 series -> A
    hipLaunchKernelGGL(scan_kernel, dim3(144), dim3(256), 0, stream, B, Au, rk, 36864);
    // o3 = pool(psp(s5)): 9216 outputs -> C
    hipLaunchKernelGGL(poolfir_kernel, dim3(9216 / 16), dim3(512), 0, stream,
                       Au, C, HQ, 64, 6, 6);
    // s6 = spike(o3): 9216 series -> A
    hipLaunchKernelGGL(scan_kernel, dim3(36), dim3(256), 0, stream, C, Au, rk, 9216);
    // p6 = psp(s6): -> B
    hipLaunchKernelGGL((fir_kernel<0>), dim3(144), dim3(512), 0, stream,
                       Au, B, HQ, 9216);
    // c4 = conv4(p6): (4,64,6,6,200) -> C
    hipLaunchKernelGGL((conv3_kernel<64, 4>), dim3(36 / 4, 16, 4), dim3(256), 0, stream,
                       B, wt4, C, 64, 6, 6);
    // s7 = spike(c4): 9216 series -> A
    hipLaunchKernelGGL(scan_kernel, dim3(36), dim3(256), 0, stream, C, Au, rk, 9216);
    // p7 = psp(s7): -> B
    hipLaunchKernelGGL((fir_kernel<0>), dim3(144), dim3(512), 0, stream,
                       Au, B, HQ, 9216);
    // fc: (4,10,200) -> C
    hipLaunchKernelGGL(fc_kernel, dim3(4, 25), dim3(128), 0, stream, B, Wfc, C);
    // final spike -> d_out: 40 series
    hipLaunchKernelGGL(spike_kernel, dim3(1), dim3(256), 0, stream, C, outp, rk, 40);
    (void)in_sizes; (void)n_in; (void)out_size; (void)ws_size;
}

// Round 4
// 875.290 us; speedup vs baseline: 1.1291x; 1.1291x over previous
//
#include <hip/hip_runtime.h>
#include <math.h>

// ---------------------------------------------------------------------------
// SNN forward: psp (K=100 alpha FIR) -> conv/pool/fc -> spike (refractory scan)
// All arithmetic mirrors the JAX reference's f32 association order.
// Round 14: split scan (parallel, packed-spike output) + round-10 dense FIR.
//   scan_kernel — 1 thread/series refractory scan, rolling prefetch, writes
//                 spikes packed 4-per-dword.
//   fir/poolfir — stage packed dwords, UNPACK AT STAGE TIME to the proven
//                 f32 LDS tile (RSTRIDE 204), then the round-10 inner loop
//                 (ds_read_b128 + 32 FMA, VGPR~40).  No serial scan phase,
//                 no per-j unpack (round-13's mistake: VGPR 124, occ 18%).
// Bit-exact: spikes are {0,1}, pack/unpack is exact, FIR order unchanged.
// ---------------------------------------------------------------------------

#define THETA 10.0f
#define RSTRIDE 204   // words per series row: 200 + pad4; 16B aligned

// HQ[i] = h[i-15] for 15<=i<=114 (h[k] = (k/10)*exp(1-k/10)), else 0. 144 entries.
// rk[i] = REF_KERNEL[i+1] = (-40*(i+1))*exp(1-(i+1)),  i=0..14
// wtN = transposed weights: wt[(ci*K*K + tap)*Co + co] = W[co][ci][tap]
__global__ void prep_kernel(const float* __restrict__ W1, const float* __restrict__ W2,
                            const float* __restrict__ W3, const float* __restrict__ W4,
                            float* HQ, float* rk,
                            float* wt1, float* wt2, float* wt3, float* wt4) {
    int i = blockIdx.x * 256 + threadIdx.x;
    if (i < 144) {
        int k = i - 15;
        float val = 0.0f;
        if (k >= 0 && k <= 99) {
            float tf = (float)k;
            float x = tf / 10.0f;
            val = x * (float)exp((double)(1.0f - x));   // same expr as prior rounds
        }
        HQ[i] = val;
    } else if (i < 160) {
        int j = i - 144;
        if (j < 15) {
            float t = (float)(j + 1);
            rk[j] = (-40.0f * t) * (float)exp((double)(1.0f - t));
        }
    } else if (i < 960) {            // W1: 16 x 50
        int j = i - 160, co = j / 50, tp = j % 50;
        wt1[tp * 16 + co] = W1[j];
    } else if (i < 5568) {           // W2: 32 x 144
        int j = i - 960, co = j / 144, tp = j % 144;
        wt2[tp * 32 + co] = W2[j];
    } else if (i < 24000) {          // W3: 64 x 288
        int j = i - 5568, co = j / 288, tp = j % 288;
        wt3[tp * 64 + co] = W3[j];
    } else if (i < 60864) {          // W4: 64 x 576
        int j = i - 24000, co = j / 576, tp = j % 576;
        wt4[tp * 64 + co] = W4[j];
    }
}

// One scan step; spike bit ORed into W.  Math identical to prior rounds:
// u = x + p[0]; s = (u>=theta); p[i] = fmaf(s, rk[i], p[i+1]); p[14]=s*rk[14].
#define SCANB(XC, BIT, W, p, rk)                                              \
    {                                                                         \
        const float u_ = (XC) + p[0];                                         \
        const bool sp_ = (u_ >= THETA);                                       \
        const float sv_ = sp_ ? 1.0f : 0.0f;                                  \
        W |= sp_ ? (BIT) : 0u;                                                \
        _Pragma("unroll")                                                     \
        for (int i_ = 0; i_ < 14; ++i_) p[i_] = fmaf(sv_, rk[i_], p[i_ + 1]); \
        p[14] = sv_ * rk[14];                                                 \
    }

// Process one float4 quad -> one packed spike dword (bytes = t0..t0+3).
#define QPROC(BV, QI)                                                         \
    {                                                                         \
        unsigned int w_ = 0u;                                                 \
        SCANB(BV.x, 1u, w_, p, rk)                                            \
        SCANB(BV.y, 0x100u, w_, p, rk)                                        \
        SCANB(BV.z, 0x10000u, w_, p, rk)                                      \
        SCANB(BV.w, 0x1000000u, w_, p, rk)                                    \
        sp[QI] = w_;                                                          \
    }

// ---------------------------------------------------------------------------
// Refractory scan, 1 thread = 1 series.  Reads 200 f32 potentials via a
// 5-quad rolling register prefetch; writes 50 packed dwords.
// ---------------------------------------------------------------------------
__global__ __launch_bounds__(256) void scan_kernel(const float* __restrict__ v,
                                                   unsigned int* __restrict__ s,
                                                   const float* __restrict__ rkt,
                                                   int n) {
    const int nid = blockIdx.x * 256 + threadIdx.x;
    if (nid >= n) return;
    float rk[15];
    #pragma unroll
    for (int i = 0; i < 15; ++i) rk[i] = rkt[i];
    float p[15];
    #pragma unroll
    for (int i = 0; i < 15; ++i) p[i] = 0.0f;
    const float4* vp4 = reinterpret_cast<const float4*>(v + (long)nid * 200);
    unsigned int* sp = s + (long)nid * 50;
    float4 b0 = vp4[0], b1 = vp4[1], b2 = vp4[2], b3 = vp4[3], b4 = vp4[4];
    #pragma unroll 1
    for (int g = 0; g < 10; ++g) {
        const int q0 = 5 * g;
        QPROC(b0, q0)
        if (g < 9) b0 = vp4[q0 + 5];
        QPROC(b1, q0 + 1)
        if (g < 9) b1 = vp4[q0 + 6];
        QPROC(b2, q0 + 2)
        if (g < 9) b2 = vp4[q0 + 7];
        QPROC(b3, q0 + 3)
        if (g < 9) b3 = vp4[q0 + 8];
        QPROC(b4, q0 + 4)
        if (g < 9) b4 = vp4[q0 + 9];
    }
}

// 16-FMA inner step, order identical to prior rounds (qw,qz,qy,qx; k
// ascending per accumulator).  hA = coeff base vector, hB = next vector.
#define FIR_STEP(A0, A1, A2, A3, qx, qy, qz, qw, hA, hB)  \
    A0 = fmaf(hA.x, qw, A0);                              \
    A1 = fmaf(hA.y, qw, A1);                              \
    A2 = fmaf(hA.z, qw, A2);                              \
    A3 = fmaf(hA.w, qw, A3);                              \
    A0 = fmaf(hA.y, qz, A0);                              \
    A1 = fmaf(hA.z, qz, A1);                              \
    A2 = fmaf(hA.w, qz, A2);                              \
    A3 = fmaf(hB.x, qz, A3);                              \
    A0 = fmaf(hA.z, qy, A0);                              \
    A1 = fmaf(hA.w, qy, A1);                              \
    A2 = fmaf(hB.x, qy, A2);                              \
    A3 = fmaf(hB.y, qy, A3);                              \
    A0 = fmaf(hA.w, qx, A0);                              \
    A1 = fmaf(hB.x, qx, A1);                              \
    A2 = fmaf(hB.y, qx, A2);                              \
    A3 = fmaf(hB.z, qx, A3);

// ---------------------------------------------------------------------------
// FIR item (8 outputs at t0=8*id): per j one b128 tile read + 32 FMA.
// Window: A=HQ4[j+2], B=HQ4[j+3], C=HQ4[j+4]; d=0 uses (A,B), d=1 uses (B,C).
// Out-of-range taps hit HQ zeros -> exact no-ops (all operands >= +0).
// jend = min(2*id,25)+1 covers both chunks exactly.  (Round-10 code.)
// ---------------------------------------------------------------------------
__device__ __forceinline__ void fir_run2(const float* __restrict__ row,
                                         const float4* __restrict__ HQ4,
                                         int t0, int jend, float4 (&acc)[2]) {
    float4 A = HQ4[2], B = HQ4[3], C = HQ4[4];
    const float* bp = row + t0 + 4;
    for (int j = 0; j <= jend; ++j) {
        const float4 qv = *reinterpret_cast<const float4*>(bp);
        const float4 N = HQ4[j + 5];
        FIR_STEP(acc[0].x, acc[0].y, acc[0].z, acc[0].w,
                 qv.x, qv.y, qv.z, qv.w, A, B)
        FIR_STEP(acc[1].x, acc[1].y, acc[1].z, acc[1].w,
                 qv.x, qv.y, qv.z, qv.w, B, C)
        A = B; B = C; C = N;
        bp -= 4;
    }
}

// Balanced wave->item table (item id i has min(2i,25)+2 j-iters; wave sums
// 60..71 vs avg 63.3).  -1 = no item.
__device__ static const signed char FIR_ITEMS[8][4] = {
    {24, 12, 8, -1}, {22, 21, 4, -1}, {20, 19, 3, -1}, {18, 17, 2, -1},
    {16, 15, 1, 0},  {13, 11, 5, -1}, {14, 10, 6, -1}, {23, 9, 7, -1}};

// Unpack one packed spike dword to a float4 of exact {0.0,1.0}.
__device__ __forceinline__ float4 unpack4(unsigned int w) {
    return make_float4((float)(w & 0xFFu), (float)((w >> 8) & 0xFFu),
                       (float)((w >> 16) & 0xFFu), (float)((w >> 24) & 0xFFu));
}

// ---------------------------------------------------------------------------
// FIR kernel.  Block = 64 series x 8 waves, f32 LDS tile [64][204].
// MODE 0: input = packed spike dwords (unpacked during staging).
// MODE 1: input = f32 {0,1} spikes (network input); staged as-is.
// ---------------------------------------------------------------------------
template <int MODE>
__global__ __launch_bounds__(512) void fir_kernel(const void* __restrict__ in,
                                                  float* __restrict__ out,
                                                  const float* __restrict__ HQ,
                                                  int n) {
    __shared__ __align__(16) float tile[64 * RSTRIDE];
    const int l = threadIdx.x & 63;
    const int w = threadIdx.x >> 6;
    const int s0 = blockIdx.x * 64;
    if (MODE == 0) {
        const unsigned int* ip = (const unsigned int*)in;
        for (int i = threadIdx.x; i < 3200; i += 512) {
            const int slot = i / 50, q = i - slot * 50;
            const unsigned int wv = ip[(long)(s0 + slot) * 50 + q];
            *reinterpret_cast<float4*>(&tile[slot * RSTRIDE + 4 * q]) = unpack4(wv);
        }
    } else {
        const float* ip = (const float*)in;
        for (int i = threadIdx.x; i < 3200; i += 512) {
            const int slot = i / 50, q = i - slot * 50;
            const int ser = s0 + slot;
            float4 v = make_float4(0.f, 0.f, 0.f, 0.f);
            if (ser < n) v = *reinterpret_cast<const float4*>(ip + (long)ser * 200 + 4 * q);
            *reinterpret_cast<float4*>(&tile[slot * RSTRIDE + 4 * q]) = v;
        }
    }
    __syncthreads();
    const bool valid = (s0 + l) < n;
    const float* row = tile + l * RSTRIDE;
    const float4* HQ4 = reinterpret_cast<const float4*>(HQ);
    float* op = out + (long)(s0 + l) * 200;
    #pragma unroll
    for (int k = 0; k < 4; ++k) {
        const int id = FIR_ITEMS[w][k];
        if (id < 0) break;
        const int t0 = 8 * id;
        const int jend = ((2 * id < 25) ? 2 * id : 25) + 1;
        float4 acc[2];
        acc[0] = make_float4(0.f, 0.f, 0.f, 0.f);
        acc[1] = make_float4(0.f, 0.f, 0.f, 0.f);
        fir_run2(row, HQ4, t0, jend, acc);
        if (valid) {
            *reinterpret_cast<float4*>(op + t0) = acc[0];
            *reinterpret_cast<float4*>(op + t0 + 4) = acc[1];
        }
    }
}

// ---------------------------------------------------------------------------
// FIR + 2x2 sum-pool (*11).  Block = 16 outputs = 64 input series
// (slot = 4*oi + pixel); input = packed spike dwords, unpacked at staging.
// Pool combine = in-order quad shuffle sum ((p0+p1)+p2)+p3 then *11 —
// bit-identical to unfused.
// ---------------------------------------------------------------------------
__global__ __launch_bounds__(512) void poolfir_kernel(const unsigned int* __restrict__ in,
                                                      float* __restrict__ out,
                                                      const float* __restrict__ HQ,
                                                      int C, int HO, int WO) {
    __shared__ __align__(16) float tile[64 * RSTRIDE];
    __shared__ int sbase[64];
    const int l = threadIdx.x & 63;
    const int w = threadIdx.x >> 6;
    const int o0 = blockIdx.x * 16;
    const int H = 2 * HO, W = 2 * WO;
    if (threadIdx.x < 64) {
        const int oi = threadIdx.x >> 2, p = threadIdx.x & 3;
        const int o = o0 + oi;
        const int wo = o % WO; int tmp = o / WO;
        const int ho = tmp % HO; tmp /= HO;
        const int c = tmp % C; const int b = tmp / C;
        sbase[threadIdx.x] = ((b * C + c) * H + 2 * ho + (p >> 1)) * W + 2 * wo + (p & 1);
    }
    __syncthreads();
    for (int i = threadIdx.x; i < 3200; i += 512) {
        const int slot = i / 50, q = i - slot * 50;
        const unsigned int wv = in[(long)sbase[slot] * 50 + q];
        *reinterpret_cast<float4*>(&tile[slot * RSTRIDE + 4 * q]) = unpack4(wv);
    }
    __syncthreads();
    const int qb = l & ~3;
    const float* row = tile + l * RSTRIDE;
    const float4* HQ4 = reinterpret_cast<const float4*>(HQ);
    float* op = out + (long)(o0 + (l >> 2)) * 200;
    auto qsum = [&](float v) -> float {
        const float v0 = __shfl(v, qb + 0);
        const float v1 = __shfl(v, qb + 1);
        const float v2 = __shfl(v, qb + 2);
        const float v3 = __shfl(v, qb + 3);
        return (((v0 + v1) + v2) + v3) * 11.0f;
    };
    #pragma unroll
    for (int k = 0; k < 4; ++k) {
        const int id = FIR_ITEMS[w][k];
        if (id < 0) break;
        const int t0 = 8 * id;
        const int jend = ((2 * id < 25) ? 2 * id : 25) + 1;
        float4 acc[2];
        acc[0] = make_float4(0.f, 0.f, 0.f, 0.f);
        acc[1] = make_float4(0.f, 0.f, 0.f, 0.f);
        fir_run2(row, HQ4, t0, jend, acc);
        #pragma unroll
        for (int d = 0; d < 2; ++d) {
            float4 r;
            r.x = qsum(acc[d].x); r.y = qsum(acc[d].y);
            r.z = qsum(acc[d].z); r.w = qsum(acc[d].w);
            if ((l & 3) == 0)
                *reinterpret_cast<float4*>(op + t0 + 4 * d) = r;
        }
    }
}

// ---------------------------------------------------------------------------
// conv1 (K=5): float4-of-t, transposed weights, 16 co accumulators.
// ---------------------------------------------------------------------------
template <int K, int PAD, int CI, int COG>
__global__ __launch_bounds__(256) void conv_kernel(const float* __restrict__ x,
                                                   const float* __restrict__ wt,
                                                   float* __restrict__ out,
                                                   int Co, int H, int W,
                                                   int HO, int WO) {
    const int l = threadIdx.x & 63;
    const int wv = threadIdx.x >> 6;
    if (l >= 50) return;
    const int p = blockIdx.x * 4 + wv;
    const int wo = p % WO, ho = p / WO;
    const int co0 = blockIdx.y * COG;
    const int b = blockIdx.z;
    const int t0 = l * 4;
    float4 acc[COG];
    #pragma unroll
    for (int c = 0; c < COG; ++c) acc[c] = make_float4(0.f, 0.f, 0.f, 0.f);
    const float* xb = x + ((long)b * CI * H * W) * 200 + t0;
    for (int ci = 0; ci < CI; ++ci) {
        #pragma unroll
        for (int kh = 0; kh < K; ++kh) {
            const int hi = ho + kh - PAD;
            if (hi < 0 || hi >= H) continue;
            #pragma unroll
            for (int kw = 0; kw < K; ++kw) {
                const int wi = wo + kw - PAD;
                if (wi < 0 || wi >= W) continue;
                const float4 v = *reinterpret_cast<const float4*>(
                    xb + ((long)(ci * H + hi) * W + wi) * 200);
                const float* wp = wt + ((ci * K + kh) * K + kw) * Co + co0;
                #pragma unroll
                for (int c = 0; c < COG; ++c) {
                    const float wv_ = wp[c];
                    acc[c].x = fmaf(wv_, v.x, acc[c].x);
                    acc[c].y = fmaf(wv_, v.y, acc[c].y);
                    acc[c].z = fmaf(wv_, v.z, acc[c].z);
                    acc[c].w = fmaf(wv_, v.w, acc[c].w);
                }
            }
        }
    }
    const long hwN = (long)HO * WO;
    const long ob = ((long)(b * Co + co0) * HO + ho) * WO + wo;
    #pragma unroll
    for (int c = 0; c < COG; ++c)
        *reinterpret_cast<float4*>(out + (ob + c * hwN) * 200 + t0) = acc[c];
}

// ---------------------------------------------------------------------------
// K=3 convs: ci-software-pipelined, zero-filled OOB taps (bit-exact).
// ---------------------------------------------------------------------------
template <int CI, int COG>
__global__ __launch_bounds__(256) void conv3_kernel(const float* __restrict__ x,
                                                    const float* __restrict__ wt,
                                                    float* __restrict__ out,
                                                    int Co, int H, int W) {
    const int l = threadIdx.x & 63;
    const int wv = threadIdx.x >> 6;
    if (l >= 50) return;
    const int p = blockIdx.x * 4 + wv;
    const int wo = p % W, ho = p / W;
    const int co0 = blockIdx.y * COG;
    const int b = blockIdx.z;
    const int t0 = l * 4;
    float4 acc[COG];
    #pragma unroll
    for (int c = 0; c < COG; ++c) acc[c] = make_float4(0.f, 0.f, 0.f, 0.f);

    bool vm[9];
    #pragma unroll
    for (int i = 0; i < 9; ++i) {
        const int hi = ho + i / 3 - 1, wi = wo + i % 3 - 1;
        vm[i] = (hi >= 0) && (hi < H) && (wi >= 0) && (wi < W);
    }
    const long cis = (long)H * W * 200;
    const float* pb = x + (long)b * CI * cis + ((long)(ho - 1) * W + (wo - 1)) * 200 + t0;

    float4 bufA[9], bufB[9];
    auto ld = [&](int ci, float4 (&B)[9]) {
        const float* pc = pb + ci * cis;
        #pragma unroll
        for (int i = 0; i < 9; ++i) {
            B[i] = vm[i] ? *reinterpret_cast<const float4*>(pc + ((i / 3) * W + (i % 3)) * 200)
                         : make_float4(0.f, 0.f, 0.f, 0.f);
        }
    };
    auto fm = [&](const float4 (&B)[9], int ci) {
        #pragma unroll
        for (int i = 0; i < 9; ++i) {
            const float* wp = wt + (ci * 9 + i) * Co + co0;
            #pragma unroll
            for (int c = 0; c < COG; ++c) {
                const float wv_ = wp[c];
                acc[c].x = fmaf(wv_, B[i].x, acc[c].x);
                acc[c].y = fmaf(wv_, B[i].y, acc[c].y);
                acc[c].z = fmaf(wv_, B[i].z, acc[c].z);
                acc[c].w = fmaf(wv_, B[i].w, acc[c].w);
            }
        }
    };

    ld(0, bufA);
    #pragma unroll 1
    for (int ci = 0; ci < CI; ci += 2) {
        ld(ci + 1, bufB);
        fm(bufA, ci);
        if (ci + 2 < CI) ld(ci + 2, bufA);
        fm(bufB, ci + 1);
    }

    const long hwN = (long)H * W;
    const long ob = ((long)(b * Co + co0) * H + ho) * W + wo;
    #pragma unroll
    for (int c = 0; c < COG; ++c)
        *reinterpret_cast<float4*>(out + (ob + c * hwN) * 200 + t0) = acc[c];
}

// ---------------------------------------------------------------------------
// Standalone spike scan producing f32 spikes (final fc->spike only).
// ---------------------------------------------------------------------------
__global__ __launch_bounds__(256) void spike_kernel(const float* __restrict__ v,
                                                    float* __restrict__ s,
                                                    const float* __restrict__ rkt,
                                                    int n) {
    const int nid = blockIdx.x * 256 + threadIdx.x;
    if (nid >= n) return;
    float rk[15];
    #pragma unroll
    for (int i = 0; i < 15; ++i) rk[i] = rkt[i];
    float p[15];
    #pragma unroll
    for (int i = 0; i < 15; ++i) p[i] = 0.0f;
    const float* vp = v + (long)nid * 200;
    float* sp = s + (long)nid * 200;
    for (int t = 0; t < 200; ++t) {
        const float u = vp[t] + p[0];
        const float sv = (u >= THETA) ? 1.0f : 0.0f;
        sp[t] = sv;
        #pragma unroll
        for (int i = 0; i < 14; ++i) p[i] = fmaf(sv, rk[i], p[i + 1]);
        p[14] = sv * rk[14];
    }
}

// ---------------------------------------------------------------------------
// FC: out[b,k,t] = sum_m x[b,m,t] * Wfc[k,m], m ascending (2304) — chain
// order unchanged (bit-exact).  LDS t-major xs[q][2308]: lane (k,q) reads
// 4 m's per ds_read_b128 (576 LDS issues vs 2304).  80 active lanes/block.
// ---------------------------------------------------------------------------
__global__ __launch_bounds__(128) void fc_kernel(const float* __restrict__ x,
                                                 const float* __restrict__ wf,
                                                 float* __restrict__ out) {
    __shared__ __align__(16) float xs[8 * 2308];
    const int b = blockIdx.x;          // 4
    const int t0 = blockIdx.y * 8;     // 25 chunks
    const int tid = threadIdx.x;
    const float* xb = x + (long)b * 2304 * 200 + t0;
    for (int i = tid; i < 4608; i += 128) {
        const int m = i >> 1, qh = (i & 1) * 4;
        const float4 v = *reinterpret_cast<const float4*>(xb + (long)m * 200 + qh);
        xs[(qh + 0) * 2308 + m] = v.x;
        xs[(qh + 1) * 2308 + m] = v.y;
        xs[(qh + 2) * 2308 + m] = v.z;
        xs[(qh + 3) * 2308 + m] = v.w;
    }
    __syncthreads();
    if (tid < 80) {
        const int k = tid >> 3, q = tid & 7;
        float a = 0.0f;
        const float* wp = wf + k * 2304;
        const float* xp = xs + q * 2308;
        for (int m4 = 0; m4 < 2304; m4 += 4) {
            const float4 xv = *reinterpret_cast<const float4*>(xp + m4);
            const float4 wv = *reinterpret_cast<const float4*>(wp + m4);
            a = fmaf(wv.x, xv.x, a);
            a = fmaf(wv.y, xv.y, a);
            a = fmaf(wv.z, xv.z, a);
            a = fmaf(wv.w, xv.w, a);
        }
        out[((long)b * 10 + k) * 200 + t0 + q] = a;
    }
}

extern "C" void kernel_launch(void* const* d_in, const int* in_sizes, int n_in,
                              void* d_out, int out_size, void* d_ws, size_t ws_size,
                              hipStream_t stream) {
    const float* x_in = (const float*)d_in[0];  // (4,2,50,50,200)
    const float* W1 = (const float*)d_in[1];    // (16,2,5,5)
    const float* W2 = (const float*)d_in[2];    // (32,16,3,3)
    const float* W3 = (const float*)d_in[3];    // (64,32,3,3)
    const float* W4 = (const float*)d_in[4];    // (64,64,3,3)
    const float* Wfc = (const float*)d_in[5];   // (10,64,6,6)
    float* outp = (float*)d_out;                // (4,10,200)

    float* ws = (float*)d_ws;
    float* HQ  = ws;                  // 144 (16B aligned)
    float* rk  = ws + 144;            // 15 (+1 pad)
    float* wt1 = ws + 160;            // 800
    float* wt2 = wt1 + 800;           // 4608
    float* wt3 = wt2 + 4608;          // 18432
    float* wt4 = wt3 + 18432;         // 36864
    float* A   = wt4 + 36864;         // 7,372,800 floats (packed spikes live here)
    float* B   = A + 7372800;         // 29,491,200
    float* C   = B + 29491200;        // 14,745,600
    unsigned int* Au = (unsigned int*)A;   // packed spikes: series*50 dwords

    hipLaunchKernelGGL(prep_kernel, dim3(238), dim3(256), 0, stream,
                       W1, W2, W3, W4, HQ, rk, wt1, wt2, wt3, wt4);

    // p0 = psp(input): 20000 series (input is exact {0,1} f32) -> A
    hipLaunchKernelGGL((fir_kernel<1>), dim3(313), dim3(512), 0, stream,
                       x_in, A, HQ, 20000);
    // c1 = conv1(p0): (4,16,48,48,200) -> B
    hipLaunchKernelGGL((conv_kernel<5, 1, 2, 16>), dim3(2304 / 4, 1, 4), dim3(256), 0, stream,
                       A, wt1, B, 16, 50, 50, 48, 48);
    // s1 = spike(c1): 147456 series -> packed in A (exactly 29,491,200 B)
    hipLaunchKernelGGL(scan_kernel, dim3(576), dim3(256), 0, stream, B, Au, rk, 147456);
    // o1 = pool(psp(s1)): 36864 outputs -> C
    hipLaunchKernelGGL(poolfir_kernel, dim3(36864 / 16), dim3(512), 0, stream,
                       Au, C, HQ, 16, 24, 24);
    // s2 = spike(o1): 36864 series -> A
    hipLaunchKernelGGL(scan_kernel, dim3(144), dim3(256), 0, stream, C, Au, rk, 36864);
    // p2 = psp(s2): -> B
    hipLaunchKernelGGL((fir_kernel<0>), dim3(576), dim3(512), 0, stream,
                       Au, B, HQ, 36864);
    // c2 = conv2(p2): (4,32,24,24,200) -> C
    hipLaunchKernelGGL((conv3_kernel<16, 8>), dim3(576 / 4, 4, 4), dim3(256), 0, stream,
                       B, wt2, C, 32, 24, 24);
    // s3 = spike(c2): 73728 series -> A
    hipLaunchKernelGGL(scan_kernel, dim3(288), dim3(256), 0, stream, C, Au, rk, 73728);
    // o2 = pool(psp(s3)): 18432 outputs -> B
    hipLaunchKernelGGL(poolfir_kernel, dim3(18432 / 16), dim3(512), 0, stream,
                       Au, B, HQ, 32, 12, 12);
    // s4 = spike(o2): 18432 series -> A
    hipLaunchKernelGGL(scan_kernel, dim3(72), dim3(256), 0, stream, B, Au, rk, 18432);
    // p4 = psp(s4): -> C
    hipLaunchKernelGGL((fir_kernel<0>), dim3(288), dim3(512), 0, stream,
                       Au, C, HQ, 18432);
    // c3 = conv3(p4): (4,64,12,12,200) -> B
    hipLaunchKernelGGL((conv3_kernel<32, 8>), dim3(144 / 4, 8, 4), dim3(256), 0, stream,
                       C, wt3, B, 64, 12, 12);
    // s5 = spike(c3): 36864 series -> A
    hipLaunchKernelGGL(scan_kernel, dim3(144), dim3(256), 0, stream, B, Au, rk, 36864);
    // o3 = pool(psp(s5)): 9216 outputs -> C
    hipLaunchKernelGGL(poolfir_kernel, dim3(9216 / 16), dim3(512), 0, stream,
                       Au, C, HQ, 64, 6, 6);
    // s6 = spike(o3): 9216 series -> A
    hipLaunchKernelGGL(scan_kernel, dim3(36), dim3(256), 0, stream, C, Au, rk, 9216);
    // p6 = psp(s6): -> B
    hipLaunchKernelGGL((fir_kernel<0>), dim3(144), dim3(512), 0, stream,
                       Au, B, HQ, 9216);
    // c4 = conv4(p6): (4,64,6,6,200) -> C
    hipLaunchKernelGGL((conv3_kernel<64, 4>), dim3(36 / 4, 16, 4), dim3(256), 0, stream,
                       B, wt4, C, 64, 6, 6);
    // s7 = spike(c4): 9216 series -> A
    hipLaunchKernelGGL(scan_kernel, dim3(36), dim3(256), 0, stream, C, Au, rk, 9216);
    // p7 = psp(s7): -> B
    hipLaunchKernelGGL((fir_kernel<0>), dim3(144), dim3(512), 0, stream,
                       Au, B, HQ, 9216);
    // fc: (4,10,200) -> C
    hipLaunchKernelGGL(fc_kernel, dim3(4, 25), dim3(128), 0, stream, B, Wfc, C);
    // final spike -> d_out: 40 series
    hipLaunchKernelGGL(spike_kernel, dim3(1), dim3(256), 0, stream, C, outp, rk, 40);
    (void)in_sizes; (void)n_in; (void)out_size; (void)ws_size;
}

// Round 5
// 779.573 us; speedup vs baseline: 1.2677x; 1.1228x over previous
//
#include <hip/hip_runtime.h>
#include <math.h>

// ---------------------------------------------------------------------------
// SNN forward: psp (K=100 alpha FIR) -> conv/pool/fc -> spike (refractory scan)
// All arithmetic mirrors the JAX reference's f32 association order.
// Round 15: fused round-10 architecture restored (known 675 us), with the
// scan wall amortized: 128-series tiles, 1024 threads (16 waves), TWO scan
// waves in parallel (rows 0-63 / 64-127).  Scan wall (7600 cyc) now covers
// 128 series instead of 64.  FIR partition: waves 0-7 = FIR_ITEMS[w] on
// rows 0-63, waves 8-15 same items on rows 64-127 (identical balance).
// LDS 104.4 KB dynamic (gfx950 has 160 KB/CU).  Bit-exact: all math and
// per-series work identical to the 675-us version; only geometry changed.
// ---------------------------------------------------------------------------

#define THETA 10.0f
#define RSTRIDE 204   // words per series row: 200 + pad4; 16B aligned

// HQ[i] = h[i-15] for 15<=i<=114 (h[k] = (k/10)*exp(1-k/10)), else 0. 144 entries.
// rk[i] = REF_KERNEL[i+1] = (-40*(i+1))*exp(1-(i+1)),  i=0..14
// wtN = transposed weights: wt[(ci*K*K + tap)*Co + co] = W[co][ci][tap]
__global__ void prep_kernel(const float* __restrict__ W1, const float* __restrict__ W2,
                            const float* __restrict__ W3, const float* __restrict__ W4,
                            float* HQ, float* rk,
                            float* wt1, float* wt2, float* wt3, float* wt4) {
    int i = blockIdx.x * 256 + threadIdx.x;
    if (i < 144) {
        int k = i - 15;
        float val = 0.0f;
        if (k >= 0 && k <= 99) {
            float tf = (float)k;
            float x = tf / 10.0f;
            val = x * (float)exp((double)(1.0f - x));   // same expr as prior rounds
        }
        HQ[i] = val;
    } else if (i < 160) {
        int j = i - 144;
        if (j < 15) {
            float t = (float)(j + 1);
            rk[j] = (-40.0f * t) * (float)exp((double)(1.0f - t));
        }
    } else if (i < 960) {            // W1: 16 x 50
        int j = i - 160, co = j / 50, tp = j % 50;
        wt1[tp * 16 + co] = W1[j];
    } else if (i < 5568) {           // W2: 32 x 144
        int j = i - 960, co = j / 144, tp = j % 144;
        wt2[tp * 32 + co] = W2[j];
    } else if (i < 24000) {          // W3: 64 x 288
        int j = i - 5568, co = j / 288, tp = j % 288;
        wt3[tp * 64 + co] = W3[j];
    } else if (i < 60864) {          // W4: 64 x 576
        int j = i - 24000, co = j / 576, tp = j % 576;
        wt4[tp * 64 + co] = W4[j];
    }
}

// 4 sequential scan steps on a float4 (ascending t), identical math.
#define SCAN4(XV, p, rk)                                          \
    {                                                             \
        float u_, sv_;                                            \
        u_ = XV.x + p[0]; sv_ = (u_ >= THETA) ? 1.0f : 0.0f;      \
        XV.x = sv_;                                               \
        _Pragma("unroll")                                         \
        for (int i_ = 0; i_ < 14; ++i_) p[i_] = fmaf(sv_, rk[i_], p[i_ + 1]); \
        p[14] = sv_ * rk[14];                                     \
        u_ = XV.y + p[0]; sv_ = (u_ >= THETA) ? 1.0f : 0.0f;      \
        XV.y = sv_;                                               \
        _Pragma("unroll")                                         \
        for (int i_ = 0; i_ < 14; ++i_) p[i_] = fmaf(sv_, rk[i_], p[i_ + 1]); \
        p[14] = sv_ * rk[14];                                     \
        u_ = XV.z + p[0]; sv_ = (u_ >= THETA) ? 1.0f : 0.0f;      \
        XV.z = sv_;                                               \
        _Pragma("unroll")                                         \
        for (int i_ = 0; i_ < 14; ++i_) p[i_] = fmaf(sv_, rk[i_], p[i_ + 1]); \
        p[14] = sv_ * rk[14];                                     \
        u_ = XV.w + p[0]; sv_ = (u_ >= THETA) ? 1.0f : 0.0f;      \
        XV.w = sv_;                                               \
        _Pragma("unroll")                                         \
        for (int i_ = 0; i_ < 14; ++i_) p[i_] = fmaf(sv_, rk[i_], p[i_ + 1]); \
        p[14] = sv_ * rk[14];                                     \
    }

// 16-FMA inner step, order identical to prior rounds (qw,qz,qy,qx; k
// ascending per accumulator).  hA = coeff base vector, hB = next vector.
#define FIR_STEP(A0, A1, A2, A3, qx, qy, qz, qw, hA, hB)  \
    A0 = fmaf(hA.x, qw, A0);                              \
    A1 = fmaf(hA.y, qw, A1);                              \
    A2 = fmaf(hA.z, qw, A2);                              \
    A3 = fmaf(hA.w, qw, A3);                              \
    A0 = fmaf(hA.y, qz, A0);                              \
    A1 = fmaf(hA.z, qz, A1);                              \
    A2 = fmaf(hA.w, qz, A2);                              \
    A3 = fmaf(hB.x, qz, A3);                              \
    A0 = fmaf(hA.z, qy, A0);                              \
    A1 = fmaf(hA.w, qy, A1);                              \
    A2 = fmaf(hB.x, qy, A2);                              \
    A3 = fmaf(hB.y, qy, A3);                              \
    A0 = fmaf(hA.w, qx, A0);                              \
    A1 = fmaf(hB.x, qx, A1);                              \
    A2 = fmaf(hB.y, qx, A2);                              \
    A3 = fmaf(hB.z, qx, A3);

// ---------------------------------------------------------------------------
// FIR item (8 outputs at t0=8*id): per j one b128 tile read + 32 FMA.
// Window: A=HQ4[j+2], B=HQ4[j+3], C=HQ4[j+4]; d=0 uses (A,B), d=1 uses (B,C).
// Out-of-range taps hit HQ zeros -> exact no-ops (all operands >= +0).
// jend = min(2*id,25)+1 covers both chunks exactly.
// ---------------------------------------------------------------------------
__device__ __forceinline__ void fir_run2(const float* __restrict__ row,
                                         const float4* __restrict__ HQ4,
                                         int t0, int jend, float4 (&acc)[2]) {
    float4 A = HQ4[2], B = HQ4[3], C = HQ4[4];
    const float* bp = row + t0 + 4;
    for (int j = 0; j <= jend; ++j) {
        const float4 qv = *reinterpret_cast<const float4*>(bp);
        const float4 N = HQ4[j + 5];
        FIR_STEP(acc[0].x, acc[0].y, acc[0].z, acc[0].w,
                 qv.x, qv.y, qv.z, qv.w, A, B)
        FIR_STEP(acc[1].x, acc[1].y, acc[1].z, acc[1].w,
                 qv.x, qv.y, qv.z, qv.w, B, C)
        A = B; B = C; C = N;
        bp -= 4;
    }
}

// Balanced wave->item table (item id i has min(2i,25)+2 j-iters; wave sums
// 60..71 vs avg 63.3).  -1 = no item.  Used by waves w and w+8 (row halves).
__device__ static const signed char FIR_ITEMS[8][4] = {
    {24, 12, 8, -1}, {22, 21, 4, -1}, {20, 19, 3, -1}, {18, 17, 2, -1},
    {16, 15, 1, 0},  {13, 11, 5, -1}, {14, 10, 6, -1}, {23, 9, 7, -1}};

// ---------------------------------------------------------------------------
// Fused [spike ->] psp.  Block = 128 series x 16 waves, dynamic LDS tile
// [128][204].  Scan: waves 0 and 1 in parallel (64 rows each).  FIR: wave w
// handles rows ((w&8)<<3)+lane with items FIR_ITEMS[w&7].
// ---------------------------------------------------------------------------
template <bool SCAN>
__global__ __launch_bounds__(1024) void spikepsp_kernel(const float* __restrict__ in,
                                                        float* __restrict__ out,
                                                        const float* __restrict__ HQ,
                                                        const float* __restrict__ rkt,
                                                        int n) {
    extern __shared__ __align__(16) float tile[];   // 128 * RSTRIDE floats
    const int l = threadIdx.x & 63;
    const int w = threadIdx.x >> 6;
    const int s0 = blockIdx.x * 128;
    for (int i = threadIdx.x; i < 6400; i += 1024) {
        const int slot = i / 50, q = i - slot * 50;
        const int ser = s0 + slot;
        float4 v = make_float4(0.f, 0.f, 0.f, 0.f);
        if (ser < n) v = *reinterpret_cast<const float4*>(in + (long)ser * 200 + 4 * q);
        *reinterpret_cast<float4*>(&tile[slot * RSTRIDE + 4 * q]) = v;
    }
    __syncthreads();
    if (SCAN) {
        if (w < 2) {
            float rk[15];
            #pragma unroll
            for (int i = 0; i < 15; ++i) rk[i] = rkt[i];
            float p[15];
            #pragma unroll
            for (int i = 0; i < 15; ++i) p[i] = 0.0f;
            float* row = tile + (w * 64 + l) * RSTRIDE;
            for (int tq = 0; tq < 50; ++tq) {
                float4 xv = *reinterpret_cast<const float4*>(&row[4 * tq]);
                SCAN4(xv, p, rk)
                *reinterpret_cast<float4*>(&row[4 * tq]) = xv;
            }
        }
        __syncthreads();
    }
    const int r = ((w & 8) << 3) + l;           // row 0..127
    const bool valid = (s0 + r) < n;
    const float* row = tile + r * RSTRIDE;
    const float4* HQ4 = reinterpret_cast<const float4*>(HQ);
    float* op = out + (long)(s0 + r) * 200;
    #pragma unroll
    for (int k = 0; k < 4; ++k) {
        const int id = FIR_ITEMS[w & 7][k];
        if (id < 0) break;
        const int t0 = 8 * id;
        const int jend = ((2 * id < 25) ? 2 * id : 25) + 1;
        float4 acc[2];
        acc[0] = make_float4(0.f, 0.f, 0.f, 0.f);
        acc[1] = make_float4(0.f, 0.f, 0.f, 0.f);
        fir_run2(row, HQ4, t0, jend, acc);
        if (valid) {
            *reinterpret_cast<float4*>(op + t0) = acc[0];
            *reinterpret_cast<float4*>(op + t0 + 4) = acc[1];
        }
    }
}

// ---------------------------------------------------------------------------
// Fused spike -> psp -> 2x2 sum-pool (*11).  Block = 32 outputs = 128 input
// series (slot = 4*oi + pixel), 16 waves.  Pool combine = in-order quad
// shuffle sum ((p0+p1)+p2)+p3 then *11 — bit-identical to unfused.
// ---------------------------------------------------------------------------
__global__ __launch_bounds__(1024) void spikepsppool_kernel(const float* __restrict__ in,
                                                            float* __restrict__ out,
                                                            const float* __restrict__ HQ,
                                                            const float* __restrict__ rkt,
                                                            int C, int HO, int WO) {
    extern __shared__ __align__(16) float tile[];   // 128*RSTRIDE floats + 128 ints
    int* sbase = (int*)(tile + 128 * RSTRIDE);
    const int l = threadIdx.x & 63;
    const int w = threadIdx.x >> 6;
    const int o0 = blockIdx.x * 32;
    const int H = 2 * HO, W = 2 * WO;
    if (threadIdx.x < 128) {
        const int oi = threadIdx.x >> 2, p = threadIdx.x & 3;
        const int o = o0 + oi;
        const int wo = o % WO; int tmp = o / WO;
        const int ho = tmp % HO; tmp /= HO;
        const int c = tmp % C; const int b = tmp / C;
        sbase[threadIdx.x] = ((b * C + c) * H + 2 * ho + (p >> 1)) * W + 2 * wo + (p & 1);
    }
    __syncthreads();
    for (int i = threadIdx.x; i < 6400; i += 1024) {
        const int slot = i / 50, q = i - slot * 50;
        const float4 v = *reinterpret_cast<const float4*>(in + (long)sbase[slot] * 200 + 4 * q);
        *reinterpret_cast<float4*>(&tile[slot * RSTRIDE + 4 * q]) = v;
    }
    __syncthreads();
    if (w < 2) {
        float rk[15];
        #pragma unroll
        for (int i = 0; i < 15; ++i) rk[i] = rkt[i];
        float p[15];
        #pragma unroll
        for (int i = 0; i < 15; ++i) p[i] = 0.0f;
        float* row = tile + (w * 64 + l) * RSTRIDE;
        for (int tq = 0; tq < 50; ++tq) {
            float4 xv = *reinterpret_cast<const float4*>(&row[4 * tq]);
            SCAN4(xv, p, rk)
            *reinterpret_cast<float4*>(&row[4 * tq]) = xv;
        }
    }
    __syncthreads();
    const int r = ((w & 8) << 3) + l;           // row 0..127
    const int qb = l & ~3;
    const float* row = tile + r * RSTRIDE;
    const float4* HQ4 = reinterpret_cast<const float4*>(HQ);
    float* op = out + (long)(o0 + (r >> 2)) * 200;
    auto qsum = [&](float v) -> float {
        const float v0 = __shfl(v, qb + 0);
        const float v1 = __shfl(v, qb + 1);
        const float v2 = __shfl(v, qb + 2);
        const float v3 = __shfl(v, qb + 3);
        return (((v0 + v1) + v2) + v3) * 11.0f;
    };
    #pragma unroll
    for (int k = 0; k < 4; ++k) {
        const int id = FIR_ITEMS[w & 7][k];
        if (id < 0) break;
        const int t0 = 8 * id;
        const int jend = ((2 * id < 25) ? 2 * id : 25) + 1;
        float4 acc[2];
        acc[0] = make_float4(0.f, 0.f, 0.f, 0.f);
        acc[1] = make_float4(0.f, 0.f, 0.f, 0.f);
        fir_run2(row, HQ4, t0, jend, acc);
        #pragma unroll
        for (int d = 0; d < 2; ++d) {
            float4 r4;
            r4.x = qsum(acc[d].x); r4.y = qsum(acc[d].y);
            r4.z = qsum(acc[d].z); r4.w = qsum(acc[d].w);
            if ((l & 3) == 0)
                *reinterpret_cast<float4*>(op + t0 + 4 * d) = r4;
        }
    }
}

// ---------------------------------------------------------------------------
// conv1 (K=5): float4-of-t, transposed weights, 16 co accumulators.
// ---------------------------------------------------------------------------
template <int K, int PAD, int CI, int COG>
__global__ __launch_bounds__(256) void conv_kernel(const float* __restrict__ x,
                                                   const float* __restrict__ wt,
                                                   float* __restrict__ out,
                                                   int Co, int H, int W,
                                                   int HO, int WO) {
    const int l = threadIdx.x & 63;
    const int wv = threadIdx.x >> 6;
    if (l >= 50) return;
    const int p = blockIdx.x * 4 + wv;
    const int wo = p % WO, ho = p / WO;
    const int co0 = blockIdx.y * COG;
    const int b = blockIdx.z;
    const int t0 = l * 4;
    float4 acc[COG];
    #pragma unroll
    for (int c = 0; c < COG; ++c) acc[c] = make_float4(0.f, 0.f, 0.f, 0.f);
    const float* xb = x + ((long)b * CI * H * W) * 200 + t0;
    for (int ci = 0; ci < CI; ++ci) {
        #pragma unroll
        for (int kh = 0; kh < K; ++kh) {
            const int hi = ho + kh - PAD;
            if (hi < 0 || hi >= H) continue;
            #pragma unroll
            for (int kw = 0; kw < K; ++kw) {
                const int wi = wo + kw - PAD;
                if (wi < 0 || wi >= W) continue;
                const float4 v = *reinterpret_cast<const float4*>(
                    xb + ((long)(ci * H + hi) * W + wi) * 200);
                const float* wp = wt + ((ci * K + kh) * K + kw) * Co + co0;
                #pragma unroll
                for (int c = 0; c < COG; ++c) {
                    const float wv_ = wp[c];
                    acc[c].x = fmaf(wv_, v.x, acc[c].x);
                    acc[c].y = fmaf(wv_, v.y, acc[c].y);
                    acc[c].z = fmaf(wv_, v.z, acc[c].z);
                    acc[c].w = fmaf(wv_, v.w, acc[c].w);
                }
            }
        }
    }
    const long hwN = (long)HO * WO;
    const long ob = ((long)(b * Co + co0) * HO + ho) * WO + wo;
    #pragma unroll
    for (int c = 0; c < COG; ++c)
        *reinterpret_cast<float4*>(out + (ob + c * hwN) * 200 + t0) = acc[c];
}

// ---------------------------------------------------------------------------
// K=3 convs: ci-software-pipelined, zero-filled OOB taps (bit-exact).
// ---------------------------------------------------------------------------
template <int CI, int COG>
__global__ __launch_bounds__(256) void conv3_kernel(const float* __restrict__ x,
                                                    const float* __restrict__ wt,
                                                    float* __restrict__ out,
                                                    int Co, int H, int W) {
    const int l = threadIdx.x & 63;
    const int wv = threadIdx.x >> 6;
    if (l >= 50) return;
    const int p = blockIdx.x * 4 + wv;
    const int wo = p % W, ho = p / W;
    const int co0 = blockIdx.y * COG;
    const int b = blockIdx.z;
    const int t0 = l * 4;
    float4 acc[COG];
    #pragma unroll
    for (int c = 0; c < COG; ++c) acc[c] = make_float4(0.f, 0.f, 0.f, 0.f);

    bool vm[9];
    #pragma unroll
    for (int i = 0; i < 9; ++i) {
        const int hi = ho + i / 3 - 1, wi = wo + i % 3 - 1;
        vm[i] = (hi >= 0) && (hi < H) && (wi >= 0) && (wi < W);
    }
    const long cis = (long)H * W * 200;
    const float* pb = x + (long)b * CI * cis + ((long)(ho - 1) * W + (wo - 1)) * 200 + t0;

    float4 bufA[9], bufB[9];
    auto ld = [&](int ci, float4 (&B)[9]) {
        const float* pc = pb + ci * cis;
        #pragma unroll
        for (int i = 0; i < 9; ++i) {
            B[i] = vm[i] ? *reinterpret_cast<const float4*>(pc + ((i / 3) * W + (i % 3)) * 200)
                         : make_float4(0.f, 0.f, 0.f, 0.f);
        }
    };
    auto fm = [&](const float4 (&B)[9], int ci) {
        #pragma unroll
        for (int i = 0; i < 9; ++i) {
            const float* wp = wt + (ci * 9 + i) * Co + co0;
            #pragma unroll
            for (int c = 0; c < COG; ++c) {
                const float wv_ = wp[c];
                acc[c].x = fmaf(wv_, B[i].x, acc[c].x);
                acc[c].y = fmaf(wv_, B[i].y, acc[c].y);
                acc[c].z = fmaf(wv_, B[i].z, acc[c].z);
                acc[c].w = fmaf(wv_, B[i].w, acc[c].w);
            }
        }
    };

    ld(0, bufA);
    #pragma unroll 1
    for (int ci = 0; ci < CI; ci += 2) {
        ld(ci + 1, bufB);
        fm(bufA, ci);
        if (ci + 2 < CI) ld(ci + 2, bufA);
        fm(bufB, ci + 1);
    }

    const long hwN = (long)H * W;
    const long ob = ((long)(b * Co + co0) * H + ho) * W + wo;
    #pragma unroll
    for (int c = 0; c < COG; ++c)
        *reinterpret_cast<float4*>(out + (ob + c * hwN) * 200 + t0) = acc[c];
}

// ---------------------------------------------------------------------------
// Standalone spike scan (only the tiny final fc->spike uses this).
// ---------------------------------------------------------------------------
__global__ __launch_bounds__(256) void spike_kernel(const float* __restrict__ v,
                                                    float* __restrict__ s,
                                                    const float* __restrict__ rkt,
                                                    int n) {
    const int nid = blockIdx.x * 256 + threadIdx.x;
    if (nid >= n) return;
    float rk[15];
    #pragma unroll
    for (int i = 0; i < 15; ++i) rk[i] = rkt[i];
    float p[15];
    #pragma unroll
    for (int i = 0; i < 15; ++i) p[i] = 0.0f;
    const float* vp = v + (long)nid * 200;
    float* sp = s + (long)nid * 200;
    for (int t = 0; t < 200; ++t) {
        const float u = vp[t] + p[0];
        const float sv = (u >= THETA) ? 1.0f : 0.0f;
        sp[t] = sv;
        #pragma unroll
        for (int i = 0; i < 14; ++i) p[i] = fmaf(sv, rk[i], p[i + 1]);
        p[14] = sv * rk[14];
    }
}

// ---------------------------------------------------------------------------
// FC: out[b,k,t] = sum_m x[b,m,t] * Wfc[k,m], m ascending (2304) — chain
// order unchanged (bit-exact).  LDS t-major xs[q][2308]: lane (k,q) reads
// 4 m's per ds_read_b128 (576 LDS issues vs 2304).  80 active lanes/block.
// ---------------------------------------------------------------------------
__global__ __launch_bounds__(128) void fc_kernel(const float* __restrict__ x,
                                                 const float* __restrict__ wf,
                                                 float* __restrict__ out) {
    __shared__ __align__(16) float xs[8 * 2308];
    const int b = blockIdx.x;          // 4
    const int t0 = blockIdx.y * 8;     // 25 chunks
    const int tid = threadIdx.x;
    const float* xb = x + (long)b * 2304 * 200 + t0;
    for (int i = tid; i < 4608; i += 128) {
        const int m = i >> 1, qh = (i & 1) * 4;
        const float4 v = *reinterpret_cast<const float4*>(xb + (long)m * 200 + qh);
        xs[(qh + 0) * 2308 + m] = v.x;
        xs[(qh + 1) * 2308 + m] = v.y;
        xs[(qh + 2) * 2308 + m] = v.z;
        xs[(qh + 3) * 2308 + m] = v.w;
    }
    __syncthreads();
    if (tid < 80) {
        const int k = tid >> 3, q = tid & 7;
        float a = 0.0f;
        const float* wp = wf + k * 2304;
        const float* xp = xs + q * 2308;
        for (int m4 = 0; m4 < 2304; m4 += 4) {
            const float4 xv = *reinterpret_cast<const float4*>(xp + m4);
            const float4 wv = *reinterpret_cast<const float4*>(wp + m4);
            a = fmaf(wv.x, xv.x, a);
            a = fmaf(wv.y, xv.y, a);
            a = fmaf(wv.z, xv.z, a);
            a = fmaf(wv.w, xv.w, a);
        }
        out[((long)b * 10 + k) * 200 + t0 + q] = a;
    }
}

extern "C" void kernel_launch(void* const* d_in, const int* in_sizes, int n_in,
                              void* d_out, int out_size, void* d_ws, size_t ws_size,
                              hipStream_t stream) {
    const float* x_in = (const float*)d_in[0];  // (4,2,50,50,200)
    const float* W1 = (const float*)d_in[1];    // (16,2,5,5)
    const float* W2 = (const float*)d_in[2];    // (32,16,3,3)
    const float* W3 = (const float*)d_in[3];    // (64,32,3,3)
    const float* W4 = (const float*)d_in[4];    // (64,64,3,3)
    const float* Wfc = (const float*)d_in[5];   // (10,64,6,6)
    float* outp = (float*)d_out;                // (4,10,200)

    float* ws = (float*)d_ws;
    float* HQ  = ws;                  // 144 (16B aligned)
    float* rk  = ws + 144;            // 15 (+1 pad)
    float* wt1 = ws + 160;            // 800
    float* wt2 = wt1 + 800;           // 4608
    float* wt3 = wt2 + 4608;          // 18432
    float* wt4 = wt3 + 18432;         // 36864
    float* A   = wt4 + 36864;         // 7,372,800
    float* B   = A + 7372800;         // 29,491,200
    float* C   = B + 29491200;        // 14,745,600

    // Allow 104.4 KB (+sbase) dynamic LDS per block (gfx950: 160 KB/CU).
    const int DYN_PSP  = 128 * RSTRIDE * 4;            // 104448 B
    const int DYN_POOL = 128 * RSTRIDE * 4 + 128 * 4;  // 104960 B
    static bool attr_done = false;
    if (!attr_done) {
        hipFuncSetAttribute(reinterpret_cast<const void*>(&spikepsp_kernel<false>),
                            hipFuncAttributeMaxDynamicSharedMemorySize, DYN_POOL);
        hipFuncSetAttribute(reinterpret_cast<const void*>(&spikepsp_kernel<true>),
                            hipFuncAttributeMaxDynamicSharedMemorySize, DYN_POOL);
        hipFuncSetAttribute(reinterpret_cast<const void*>(&spikepsppool_kernel),
                            hipFuncAttributeMaxDynamicSharedMemorySize, DYN_POOL);
        attr_done = true;
    }

    hipLaunchKernelGGL(prep_kernel, dim3(238), dim3(256), 0, stream,
                       W1, W2, W3, W4, HQ, rk, wt1, wt2, wt3, wt4);

    // p0 = psp(input): 20000 series (no scan)
    hipLaunchKernelGGL((spikepsp_kernel<false>), dim3(157), dim3(1024), DYN_PSP, stream,
                       x_in, A, HQ, rk, 20000);
    // c1 = conv1(p0): (4,16,48,48,200)
    hipLaunchKernelGGL((conv_kernel<5, 1, 2, 16>), dim3(2304 / 4, 1, 4), dim3(256), 0, stream,
                       A, wt1, B, 16, 50, 50, 48, 48);
    // o1 = pool(psp(spike(c1))): 36864 outputs (147456 input series)
    hipLaunchKernelGGL(spikepsppool_kernel, dim3(36864 / 32), dim3(1024), DYN_POOL, stream,
                       B, A, HQ, rk, 16, 24, 24);
    // p2 = psp(spike(o1)): 36864 series
    hipLaunchKernelGGL((spikepsp_kernel<true>), dim3(36864 / 128), dim3(1024), DYN_PSP, stream,
                       A, B, HQ, rk, 36864);
    // c2 = conv2(p2): (4,32,24,24,200)
    hipLaunchKernelGGL((conv3_kernel<16, 8>), dim3(576 / 4, 4, 4), dim3(256), 0, stream,
                       B, wt2, C, 32, 24, 24);
    // o2 = pool(psp(spike(c2))): 18432 outputs
    hipLaunchKernelGGL(spikepsppool_kernel, dim3(18432 / 32), dim3(1024), DYN_POOL, stream,
                       C, A, HQ, rk, 32, 12, 12);
    // p4 = psp(spike(o2)): 18432 series
    hipLaunchKernelGGL((spikepsp_kernel<true>), dim3(18432 / 128), dim3(1024), DYN_PSP, stream,
                       A, B, HQ, rk, 18432);
    // c3 = conv3(p4): (4,64,12,12,200)
    hipLaunchKernelGGL((conv3_kernel<32, 8>), dim3(144 / 4, 8, 4), dim3(256), 0, stream,
                       B, wt3, C, 64, 12, 12);
    // o3 = pool(psp(spike(c3))): 9216 outputs
    hipLaunchKernelGGL(spikepsppool_kernel, dim3(9216 / 32), dim3(1024), DYN_POOL, stream,
                       C, A, HQ, rk, 64, 6, 6);
    // p6 = psp(spike(o3)): 9216 series
    hipLaunchKernelGGL((spikepsp_kernel<true>), dim3(9216 / 128), dim3(1024), DYN_PSP, stream,
                       A, B, HQ, rk, 9216);
    // c4 = conv4(p6): (4,64,6,6,200)
    hipLaunchKernelGGL((conv3_kernel<64, 4>), dim3(36 / 4, 16, 4), dim3(256), 0, stream,
                       B, wt4, C, 64, 6, 6);
    // p7 = psp(spike(c4)): 9216 series
    hipLaunchKernelGGL((spikepsp_kernel<true>), dim3(9216 / 128), dim3(1024), DYN_PSP, stream,
                       C, B, HQ, rk, 9216);
    // fc: (4,10,200) — block per (b, 8-t chunk), 128 threads
    hipLaunchKernelGGL(fc_kernel, dim3(4, 25), dim3(128), 0, stream, B, Wfc, A);
    // final spike -> d_out: 40 series
    hipLaunchKernelGGL(spike_kernel, dim3(1), dim3(256), 0, stream, A, outp, rk, 40);
    (void)in_sizes; (void)n_in; (void)out_size; (void)ws_size;
}